// Round 8
// baseline (543.578 us; speedup 1.0000x reference)
//
#include <hip/hip_runtime.h>
#include <math.h>

#define CDIM 256
#define HD 8
#define DD 32
#define NT 3
#define ET 5
#define QWC (ET * CDIM)   // 1280

typedef unsigned short u16;
typedef __attribute__((ext_vector_type(8))) short s16x8;
typedef __attribute__((ext_vector_type(4))) float f32x4;

__device__ __forceinline__ float b2f(u16 u) { return __uint_as_float(((unsigned)u) << 16); }
__device__ __forceinline__ u16 f2b(float x) {
    unsigned u = __float_as_uint(x);
    return (u16)((u + 0x7FFF + ((u >> 16) & 1)) >> 16);
}

// ================= node-type buckets (atomic-free, stable) =================
__global__ void bhist_k(const int* __restrict__ ntype, int N, int nblk, int* __restrict__ bcnt) {
    __shared__ int wc[4][NT];
    int b = blockIdx.x, tid = threadIdx.x, lane = tid & 63, w = tid >> 6;
    int i = b * 256 + tid;
    int t = (i < N) ? ntype[i] : -1;
#pragma unroll
    for (int r = 0; r < NT; ++r) {
        unsigned long long m = __ballot(t == r);
        if (lane == 0) wc[w][r] = __popcll(m);
    }
    __syncthreads();
    if (tid < NT) bcnt[tid * nblk + b] = wc[0][tid] + wc[1][tid] + wc[2][tid] + wc[3][tid];
}

__global__ void bscan_k(const int* __restrict__ bcnt, int* __restrict__ base,
                        int* __restrict__ off, int total, int nblk, int N) {
    __shared__ int s[1024];
    int t = threadIdx.x;
    int v = (t < total) ? bcnt[t] : 0;
    s[t] = v; __syncthreads();
    for (int o = 1; o < 1024; o <<= 1) {
        int u = (t >= o) ? s[t - o] : 0; __syncthreads();
        s[t] += u; __syncthreads();
    }
    if (t < total) base[t] = s[t] - v;
    if (t < NT) off[t] = s[t * nblk] - bcnt[t * nblk];
    if (t == NT) off[NT] = N;
}

__global__ void bscatter_k(const int* __restrict__ ntype, int N, int nblk,
                           const int* __restrict__ base, int* __restrict__ perm) {
    __shared__ int wc[4][NT];
    __shared__ int woff[4][NT];
    int b = blockIdx.x, tid = threadIdx.x, lane = tid & 63, w = tid >> 6;
    int i = b * 256 + tid;
    int t = (i < N) ? ntype[i] : -1;
    unsigned long long mlt = (1ULL << lane) - 1;
    int rank = 0;
#pragma unroll
    for (int r = 0; r < NT; ++r) {
        unsigned long long m = __ballot(t == r);
        if (lane == 0) wc[w][r] = __popcll(m);
        if (t == r) rank = __popcll(m & mlt);
    }
    __syncthreads();
    if (tid == 0) {
#pragma unroll
        for (int r = 0; r < NT; ++r) {
            int a = 0;
#pragma unroll
            for (int w0 = 0; w0 < 4; ++w0) { woff[w0][r] = a; a += wc[w0][r]; }
        }
    }
    __syncthreads();
    if (t >= 0) perm[base[t * nblk + b] + woff[w][t] + rank] = i;
}

// ================= edge counting sort by key = dst*ET + etype =================
__global__ void ehist_k(const int* __restrict__ dst, const int* __restrict__ etype, int E,
                        int* __restrict__ khist) {
    int i = blockIdx.x * 256 + threadIdx.x;
    if (i < E) atomicAdd(&khist[dst[i] * ET + etype[i]], 1);
}

__global__ void kscan1_k(const int* __restrict__ khist, int* __restrict__ kscan,
                         int* __restrict__ bsum, int KEYS) {
    __shared__ int s[256];
    int b = blockIdx.x, t = threadIdx.x, i = b * 256 + t;
    int v = (i < KEYS) ? khist[i] : 0;
    s[t] = v; __syncthreads();
    for (int o = 1; o < 256; o <<= 1) {
        int u = (t >= o) ? s[t - o] : 0; __syncthreads();
        s[t] += u; __syncthreads();
    }
    if (i < KEYS) kscan[i] = s[t] - v;
    if (t == 255) bsum[b] = s[t];
}

__global__ void kscan2_k(int* __restrict__ bsum, int NB) {
    __shared__ int s[1024];
    int t = threadIdx.x;
    int v = (t < NB) ? bsum[t] : 0;
    s[t] = v; __syncthreads();
    for (int o = 1; o < 1024; o <<= 1) {
        int u = (t >= o) ? s[t - o] : 0; __syncthreads();
        s[t] += u; __syncthreads();
    }
    if (t < NB) bsum[t] = s[t] - v;
}

__global__ void kscan3_k(int* __restrict__ kscan, const int* __restrict__ bsum, int KEYS) {
    int i = blockIdx.x * 256 + threadIdx.x;
    if (i < KEYS) kscan[i] += bsum[blockIdx.x];
}

__global__ void rowptr_k(const int* __restrict__ kscan, int* __restrict__ rowptr, int KEYS, int E) {
    int i = blockIdx.x * 256 + threadIdx.x;
    if (i < KEYS) rowptr[i] = kscan[i];
    if (i == KEYS) rowptr[KEYS] = E;
}

__global__ void escatter_k(const int* __restrict__ src, const int* __restrict__ dst,
                           const int* __restrict__ etype, int E,
                           int* __restrict__ kscan, int* __restrict__ epay) {
    int e = blockIdx.x * 256 + threadIdx.x;
    if (e < E) {
        int pos = atomicAdd(&kscan[dst[e] * ET + etype[e]], 1);
        epay[pos] = src[e];
    }
}

// ================= weight convert+transpose: W[t][k][c] f32 -> Wtb[t][c][k] bf16 ========
__global__ __launch_bounds__(256) void wconv_k(const float* __restrict__ W, u16* __restrict__ Wtb) {
    __shared__ u16 s[64][72];
    int k0 = blockIdx.x * 64, c0 = blockIdx.y * 64, t = blockIdx.z;
    const float* Wp = W + (size_t)t * CDIM * CDIM;
    int r = threadIdx.x >> 2, q = (threadIdx.x & 3) * 16;
#pragma unroll
    for (int m = 0; m < 16; m += 4) {
        float4 v = *(const float4*)(Wp + (size_t)(k0 + r) * CDIM + c0 + q + m);
        s[r][q + m + 0] = f2b(v.x); s[r][q + m + 1] = f2b(v.y);
        s[r][q + m + 2] = f2b(v.z); s[r][q + m + 3] = f2b(v.w);
    }
    __syncthreads();
    int c = threadIdx.x >> 2, kq = (threadIdx.x & 3) * 16;
    u16* op = Wtb + ((size_t)t * CDIM + c0 + c) * CDIM + k0 + kq;
#pragma unroll
    for (int m = 0; m < 16; m += 4) {
        ushort4 o;
        o.x = s[kq + m + 0][c]; o.y = s[kq + m + 1][c];
        o.z = s[kq + m + 2][c]; o.w = s[kq + m + 3][c];
        *(ushort4*)(op + m) = o;
    }
}

// ================= fold Ratt into Wq:  qf_b[t][et*256+h*32+m][c] = sum_f Wq[t][c][h32+f]*Ratt[et,h,m,f]
__global__ __launch_bounds__(256) void qfold_k(const float* __restrict__ Wq,
                                               const float* __restrict__ Ratt,
                                               u16* __restrict__ qf_b) {
    __shared__ float Ra[DD][DD];   // [m][f]
    int b = blockIdx.x;            // t*(ET*HD) + et*HD + h
    int t = b / (ET * HD);
    int eh = b % (ET * HD);
    int et = eh >> 3, h = eh & 7;
    int tid = threadIdx.x;

    ((float4*)&Ra[0][0])[tid] = ((const float4*)(Ratt + (size_t)eh * (DD * DD)))[tid];
    __syncthreads();

    int c = tid;
    const float* wr = Wq + (size_t)t * (CDIM * CDIM) + (size_t)c * CDIM + h * DD;
    float wrow[DD];
#pragma unroll
    for (int f = 0; f < DD; f += 4) {
        float4 v = *(const float4*)(wr + f);
        wrow[f] = v.x; wrow[f + 1] = v.y; wrow[f + 2] = v.z; wrow[f + 3] = v.w;
    }
    for (int m = 0; m < DD; ++m) {
        float acc = 0.f;
#pragma unroll
        for (int f = 0; f < DD; ++f) acc += wrow[f] * Ra[m][f];
        qf_b[((size_t)t * QWC + et * 256 + h * 32 + m) * CDIM + c] = f2b(acc);
    }
}

// ================= fold Rmsg into Wa:  af_b[t][col][et*256+h*32+f] = sum_m Rmsg[et,h,f,m]*Wa[t][h32+m][col]
__global__ __launch_bounds__(256) void afold_k(const float* __restrict__ Wa,
                                               const float* __restrict__ Rmsg,
                                               u16* __restrict__ af_b) {
    __shared__ float Rm[DD][DD];   // [f][m]
    int b = blockIdx.x;
    int t = b / (ET * HD);
    int eh = b % (ET * HD);
    int et = eh >> 3, h = eh & 7;
    int tid = threadIdx.x;

    ((float4*)&Rm[0][0])[tid] = ((const float4*)(Rmsg + (size_t)eh * (DD * DD)))[tid];
    __syncthreads();

    int col = tid;
    float wcol[DD];
#pragma unroll
    for (int m = 0; m < DD; ++m)
        wcol[m] = Wa[(size_t)t * (CDIM * CDIM) + (size_t)(h * 32 + m) * CDIM + col];

    u16* op = af_b + ((size_t)t * CDIM + col) * QWC + et * 256 + h * 32;
    for (int f = 0; f < DD; ++f) {
        float acc = 0.f;
#pragma unroll
        for (int m = 0; m < DD; ++m) acc += Rm[f][m] * wcol[m];
        op[f] = f2b(acc);
    }
}

// ================= MFMA typed GEMM (generalized) =================
// AMODE 0: A is f32 (convert in staging), 1: A is bf16.
// OMODE 0: bf16 out (stride bcols), 1: f32 out + sigmoid-gated blend with x (stride 256).
template<int AMODE, int OMODE>
__global__ __launch_bounds__(256) void gemm2_k(
    const void* __restrict__ Av, const u16* __restrict__ Bb, void* __restrict__ outv,
    const int* __restrict__ perm, const int* __restrict__ off, int N, int bpt,
    int K, int bcols,
    const float* __restrict__ x, const float* __restrict__ skip)
{
    __shared__ u16 As[64][40];
    __shared__ u16 Bs[64][40];
    __shared__ int ridx[64];

    int t = blockIdx.x / bpt, bi = blockIdx.x % bpt;
    int i0 = off[t] + bi * 64, iend = off[t + 1];
    if (i0 >= iend) return;
    int tid = threadIdx.x;
    int col0 = blockIdx.y * 64;

    if (tid < 64) ridx[tid] = (i0 + tid < iend) ? perm[i0 + tid] : -1;
    __syncthreads();

    int sr = tid >> 2, sq = (tid & 3) * 8;
    int ar = ridx[sr];
    const u16* bsrc = Bb + ((size_t)t * bcols + col0 + sr) * K + sq;
    const float* asrcf = (const float*)Av + (size_t)(ar >= 0 ? ar : 0) * K + sq;
    const u16* asrc16 = (const u16*)Av + (size_t)(ar >= 0 ? ar : 0) * K + sq;

    auto loadA = [&](int k0) -> uint4 {
        if (ar < 0) return make_uint4(0, 0, 0, 0);
        if (AMODE == 0) {
            float4 a0 = *(const float4*)(asrcf + k0);
            float4 a1 = *(const float4*)(asrcf + k0 + 4);
            uint4 r;
            r.x = (unsigned)f2b(a0.x) | ((unsigned)f2b(a0.y) << 16);
            r.y = (unsigned)f2b(a0.z) | ((unsigned)f2b(a0.w) << 16);
            r.z = (unsigned)f2b(a1.x) | ((unsigned)f2b(a1.y) << 16);
            r.w = (unsigned)f2b(a1.z) | ((unsigned)f2b(a1.w) << 16);
            return r;
        } else {
            return *(const uint4*)(asrc16 + k0);
        }
    };

    int lane = tid & 63, wid = tid >> 6;
    int wr = wid >> 1, wc = wid & 1;
    int l15 = lane & 15, lk = (lane >> 4) * 8;

    f32x4 acc00 = {0.f, 0.f, 0.f, 0.f}, acc01 = {0.f, 0.f, 0.f, 0.f};
    f32x4 acc10 = {0.f, 0.f, 0.f, 0.f}, acc11 = {0.f, 0.f, 0.f, 0.f};

    uint4 apre = loadA(0);
    uint4 bpre = *(const uint4*)(bsrc);

    for (int k0 = 0; k0 < K; k0 += 32) {
        __syncthreads();
        *(uint4*)&As[sr][sq] = apre;
        *(uint4*)&Bs[sr][sq] = bpre;
        __syncthreads();

        if (k0 + 32 < K) {
            apre = loadA(k0 + 32);
            bpre = *(const uint4*)(bsrc + k0 + 32);
        }

        s16x8 af0 = *(const s16x8*)&As[wr * 32 + l15][lk];
        s16x8 af1 = *(const s16x8*)&As[wr * 32 + 16 + l15][lk];
        s16x8 bf0 = *(const s16x8*)&Bs[wc * 32 + l15][lk];
        s16x8 bf1 = *(const s16x8*)&Bs[wc * 32 + 16 + l15][lk];

        acc00 = __builtin_amdgcn_mfma_f32_16x16x32_bf16(af0, bf0, acc00, 0, 0, 0);
        acc01 = __builtin_amdgcn_mfma_f32_16x16x32_bf16(af0, bf1, acc01, 0, 0, 0);
        acc10 = __builtin_amdgcn_mfma_f32_16x16x32_bf16(af1, bf0, acc10, 0, 0, 0);
        acc11 = __builtin_amdgcn_mfma_f32_16x16x32_bf16(af1, bf1, acc11, 0, 0, 0);
    }

    float alpha = 0.f, beta = 0.f;
    if (OMODE == 1) {
        alpha = 1.f / (1.f + __expf(-skip[t]));
        beta = 1.f - alpha;
    }

    int rbase = wr * 32 + (lane >> 4) * 4;
#pragma unroll
    for (int mi = 0; mi < 2; ++mi) {
#pragma unroll
        for (int r = 0; r < 4; ++r) {
            int lrow = rbase + mi * 16 + r;
            int node = ridx[lrow];
            if (node < 0) continue;
            float v0 = (mi == 0) ? acc00[r] : acc10[r];
            float v1 = (mi == 0) ? acc01[r] : acc11[r];
            int c0i = col0 + wc * 32 + l15;
            if (OMODE == 1) {
                float* out = (float*)outv;
                size_t b0 = (size_t)node * CDIM + c0i;
                out[b0]      = v0 * alpha + x[b0] * beta;
                out[b0 + 16] = v1 * alpha + x[b0 + 16] * beta;
            } else {
                u16* out = (u16*)outv;
                size_t b0 = (size_t)node * bcols + c0i;
                out[b0]      = f2b(v0);
                out[b0 + 16] = f2b(v1);
            }
        }
    }
}

// ================= gather: one wave per dst; Sv in regs across ets; svn in-place over qw ==
__global__ __launch_bounds__(256) void gather2_k(
    const u16* __restrict__ kb, const u16* __restrict__ vb, u16* __restrict__ qwsv,
    const float* __restrict__ pri, const int* __restrict__ rowptr, const int* __restrict__ epay,
    int N)
{
    int d = (blockIdx.x * 256 + threadIdx.x) >> 6;
    if (d >= N) return;
    int lane = threadIdx.x & 63, h = lane >> 3;
    const float rsD = 0.17677669529663687f;   // 1/sqrt(32)
    float dsum = 0.f;
    size_t rowb = (size_t)d * QWC + lane * 4;

    float Sv[ET][4];
#pragma unroll
    for (int et = 0; et < ET; ++et) { Sv[et][0] = Sv[et][1] = Sv[et][2] = Sv[et][3] = 0.f; }

#pragma unroll
    for (int et = 0; et < ET; ++et) {
        int key = d * ET + et;
        int p0 = rowptr[key], p1 = rowptr[key + 1];
        if (p0 >= p1) continue;
        float prif = pri[et * HD + h] * rsD;
        ushort4 qu = *(const ushort4*)(qwsv + rowb + et * 256);
        float q0 = b2f(qu.x), q1 = b2f(qu.y), q2 = b2f(qu.z), q3 = b2f(qu.w);
        for (int p = p0; p < p1; ++p) {
            int s = epay[p];
            ushort4 ku = *(const ushort4*)(kb + (size_t)s * CDIM + lane * 4);
            float tt = b2f(ku.x) * q0 + b2f(ku.y) * q1 + b2f(ku.z) * q2 + b2f(ku.w) * q3;
            tt += __shfl_xor(tt, 1, 8);
            tt += __shfl_xor(tt, 2, 8);
            tt += __shfl_xor(tt, 4, 8);
            float ex = __expf(tt * prif);
            ushort4 vu = *(const ushort4*)(vb + (size_t)s * CDIM + lane * 4);
            Sv[et][0] += ex * b2f(vu.x); Sv[et][1] += ex * b2f(vu.y);
            Sv[et][2] += ex * b2f(vu.z); Sv[et][3] += ex * b2f(vu.w);
            dsum += ex;
        }
    }

    float inv = dsum > 0.f ? 1.f / dsum : 0.f;
#pragma unroll
    for (int et = 0; et < ET; ++et) {
        ushort4 o;
        o.x = f2b(Sv[et][0] * inv); o.y = f2b(Sv[et][1] * inv);
        o.z = f2b(Sv[et][2] * inv); o.w = f2b(Sv[et][3] * inv);
        *(ushort4*)(qwsv + rowb + et * 256) = o;
    }
}

// ================= launch =================
extern "C" void kernel_launch(void* const* d_in, const int* in_sizes, int n_in,
                              void* d_out, int out_size, void* d_ws, size_t ws_size,
                              hipStream_t stream) {
    const float* x    = (const float*)d_in[0];
    const float* Wk   = (const float*)d_in[1];
    const float* Wq   = (const float*)d_in[2];
    const float* Wv   = (const float*)d_in[3];
    const float* Ratt = (const float*)d_in[4];
    const float* Rmsg = (const float*)d_in[5];
    const float* pri  = (const float*)d_in[6];
    const float* Wa   = (const float*)d_in[7];
    const float* skip = (const float*)d_in[8];
    const int* src   = (const int*)d_in[9];
    const int* dst   = (const int*)d_in[10];
    const int* etype = (const int*)d_in[11];
    const int* ntype = (const int*)d_in[12];

    int N = in_sizes[12];
    int E = in_sizes[9];
    const size_t NC = (size_t)N * CDIM;
    const int KEYS = N * ET;
    const int NB = (KEYS + 255) / 256;
    const int nblk = (N + 255) / 256;
    const size_t WTE = (size_t)NT * CDIM * CDIM;       // per weight tensor (u16 elems)
    const size_t QFE = (size_t)NT * QWC * CDIM;        // folded tensors (u16 elems)

    // ---- workspace (~186 MB) ----
    u16* kb   = (u16*)d_ws;                  // NC
    u16* vb   = kb + NC;                     // NC
    u16* qwsv = vb + NC;                     // 5*NC (qw then svn, in-place)
    u16* wtb  = qwsv + 5 * NC;               // 2*WTE (Wk, Wv transposed bf16)
    u16* qf_b = wtb + 2 * WTE;               // QFE
    u16* af_b = qf_b + QFE;                  // QFE
    int* rowptr = (int*)(af_b + QFE);        // KEYS+1  (persistent)
    int* perm   = rowptr + KEYS + 1;         // N       (persistent)
    int* epay   = perm + N;                  // E       (persistent)
    int* off    = epay + E;                  // NT+1    (persistent)
    // setup-only ints aliased into qwsv (dead before the qw GEMM writes it)
    int* khist = (int*)qwsv;                 // KEYS (zeroed)
    int* kscan = khist + KEYS;               // KEYS
    int* bsum  = kscan + KEYS;               // 1024
    int* bcnt  = bsum + 1024;                // NT*nblk
    int* base  = bcnt + NT * nblk;           // NT*nblk

    hipMemsetAsync(khist, 0, (size_t)KEYS * sizeof(int), stream);

    // node buckets (atomic-free, stable)
    bhist_k<<<nblk, 256, 0, stream>>>(ntype, N, nblk, bcnt);
    bscan_k<<<1, 1024, 0, stream>>>(bcnt, base, off, NT * nblk, nblk, N);
    bscatter_k<<<nblk, 256, 0, stream>>>(ntype, N, nblk, base, perm);

    // edge counting sort by (dst, etype) -> CSR
    ehist_k<<<(E + 255) / 256, 256, 0, stream>>>(dst, etype, E, khist);
    kscan1_k<<<NB, 256, 0, stream>>>(khist, kscan, bsum, KEYS);
    kscan2_k<<<1, 1024, 0, stream>>>(bsum, NB);
    kscan3_k<<<NB, 256, 0, stream>>>(kscan, bsum, KEYS);
    rowptr_k<<<(KEYS + 256) / 256, 256, 0, stream>>>(kscan, rowptr, KEYS, E);
    escatter_k<<<(E + 255) / 256, 256, 0, stream>>>(src, dst, etype, E, kscan, epay);

    // weight prep: Wk/Wv transpose->bf16; folded Wq*Ratt and Rmsg*Wa
    dim3 wg(4, 4, NT);
    wconv_k<<<wg, 256, 0, stream>>>(Wk, wtb + 0 * WTE);
    wconv_k<<<wg, 256, 0, stream>>>(Wv, wtb + 1 * WTE);
    qfold_k<<<NT * ET * HD, 256, 0, stream>>>(Wq, Ratt, qf_b);
    afold_k<<<NT * ET * HD, 256, 0, stream>>>(Wa, Rmsg, af_b);

    int bpt = (N + 63) / 64;

    // k, v projections (A = f32 x, converted in staging)
    gemm2_k<0, 0><<<dim3(NT * bpt, 4), 256, 0, stream>>>(x, wtb + 0 * WTE, kb, perm, off,
                                                         N, bpt, CDIM, CDIM, nullptr, nullptr);
    gemm2_k<0, 0><<<dim3(NT * bpt, 4), 256, 0, stream>>>(x, wtb + 1 * WTE, vb, perm, off,
                                                         N, bpt, CDIM, CDIM, nullptr, nullptr);

    // qw = x @ (Wq*Ratt)  -> qwsv [N][1280]   (overwrites the aliased setup ints)
    gemm2_k<0, 0><<<dim3(NT * bpt, QWC / 64), 256, 0, stream>>>(x, qf_b, qwsv, perm, off,
                                                                N, bpt, CDIM, QWC, nullptr, nullptr);

    // edge gather: svn (attn-weighted, den-normalized v-sums) in-place over qw
    gather2_k<<<(N * 64 + 255) / 256, 256, 0, stream>>>(kb, vb, qwsv, pri, rowptr, epay, N);

    // out = svn @ (Rmsg*Wa)  with sigmoid-gated skip  (K = 1280)
    gemm2_k<1, 1><<<dim3(NT * bpt, 4), 256, 0, stream>>>(qwsv, af_b, (float*)d_out, perm, off,
                                                         N, bpt, QWC, CDIM, x, skip);
}